// Round 4
// baseline (506.198 us; speedup 1.0000x reference)
//
#include <hip/hip_runtime.h>

#define B_ 8
#define N_ 8192
#define S_ 2048
#define D_ 256
#define EPS_ 1e-8f

/* ---------------- spatial grid parameters ---------------- */
#define G_    16
#define XMIN_ (-3.2f)
#define W_    0.4f
#define INVW_ 2.5f
#define NCELL (G_*G_*G_)                 /* 4096 */
#define CPAD  4104                       /* cell_start padded (u32-even) */

/* workspace layout (bytes) */
#define WS_PTS 0
#define WS_IDS (B_*S_*16)                /* 262144 */
#define WS_CEL (WS_IDS + B_*S_*2)        /* 294912 */
#define WS_NEED (WS_CEL + B_*CPAD*2)     /* 360576 */

#define TQ 128                           /* queries per block (spatial) */
#define NT 1024                          /* threads per block (spatial) */

/* ---------------- brute-force fallback params (proven R2 path) ----- */
#define TILE_Q 64
#define NTHR 512
#define NCH 8
#define CHUNK (S_ / NCH)
#define HALF (CHUNK / 2)

// Branchless stable top-3 insert (float), incumbent wins ties.
__device__ __forceinline__ void insert3(float dd, int s,
                                        float& d0, float& d1, float& d2,
                                        int& i0, int& i1, int& i2) {
    bool ca = dd < d0;
    bool cb = dd < d1;
    bool cc = dd < d2;
    int i2n = cb ? i1 : (cc ? s : i2);
    int i1n = ca ? i0 : (cb ? s : i1);
    int i0n = ca ? s : i0;
    d2 = fminf(d2, fmaxf(d1, dd));
    d1 = __builtin_amdgcn_fmed3f(d0, d1, dd);
    d0 = fminf(d0, dd);
    i0 = i0n; i1 = i1n; i2 = i2n;
}

// Top-3 insert on packed u64 composite (sortable(key)<<16 | idx).
// MERGE DISCIPLINE (R3 bug): inserting a value EQUAL to an incumbent
// duplicates it (the slot-1/2 compares pass). Therefore this may only be
// used to combine DISJOINT candidate sets, and any butterfly-merged result
// must never be fed into a second reduce. Per-lane accumulators stay
// private for the whole search; per-shell bound checks reduce into
// discarded temp copies; one final destructive merge at the end.
__device__ __forceinline__ void ins3u64(unsigned long long x,
    unsigned long long& d0, unsigned long long& d1, unsigned long long& d2) {
    bool ca = x < d0, cb = x < d1, cc = x < d2;
    d2 = cb ? d1 : (cc ? x : d2);
    d1 = ca ? d0 : (cb ? x : d1);
    d0 = ca ? x : d0;
}

/* ---------------- prep: build cell-sorted candidate lists ----------- */
__global__ __launch_bounds__(256) void grid_build_kernel(
    const float* __restrict__ xyz2,
    float4* __restrict__ wpts,
    unsigned short* __restrict__ wids,
    unsigned short* __restrict__ wcel)
{
    __shared__ unsigned int h[NCELL];
    __shared__ unsigned int part[256];
    __shared__ unsigned short cbuf[S_];
    const int b = blockIdx.x, t = threadIdx.x;
    const float* x2 = xyz2 + (size_t)b * 3 * S_;

    for (int c = t; c < NCELL; c += 256) h[c] = 0;
    __syncthreads();
    for (int s = t; s < S_; s += 256) {
        float bx = x2[s], by = x2[S_ + s], bz = x2[2*S_ + s];
        int cx = min(G_-1, max(0, (int)floorf((bx - XMIN_) * INVW_)));
        int cy = min(G_-1, max(0, (int)floorf((by - XMIN_) * INVW_)));
        int cz = min(G_-1, max(0, (int)floorf((bz - XMIN_) * INVW_)));
        int cid = (cz << 8) | (cy << 4) | cx;
        cbuf[s] = (unsigned short)cid;
        atomicAdd(&h[cid], 1u);
    }
    __syncthreads();
    unsigned int run = 0;
    for (int k = 0; k < 16; ++k) {
        unsigned int v = h[t*16 + k]; h[t*16 + k] = run; run += v;
    }
    part[t] = run;
    __syncthreads();
    if (t == 0) {
        unsigned int acc = 0;
        for (int i = 0; i < 256; ++i) { unsigned int v = part[i]; part[i] = acc; acc += v; }
    }
    __syncthreads();
    {
        unsigned int base = part[t];
        for (int k = 0; k < 16; ++k) h[t*16 + k] += base;
    }
    __syncthreads();
    unsigned short* cel = wcel + (size_t)b * CPAD;
    for (int c = t; c < NCELL; c += 256) cel[c] = (unsigned short)h[c];
    if (t == 0) cel[NCELL] = (unsigned short)S_;
    __syncthreads();   // cell_start reads of h complete before scatter mutates h
    for (int s = t; s < S_; s += 256) {
        int cid = cbuf[s];
        unsigned int pos = atomicAdd(&h[cid], 1u);
        float bx = x2[s], by = x2[S_ + s], bz = x2[2*S_ + s];
        float nn = fmaf(bz, bz, fmaf(by, by, bx * bx));   // same fma order as R2
        wpts[(size_t)b * S_ + pos] = make_float4(-2.f*bx, -2.f*by, -2.f*bz, nn);
        wids[(size_t)b * S_ + pos] = (unsigned short)s;
    }
}

/* ---------------- spatial exact 3-NN + interpolation ---------------- */
// 512 blocks x 1024 thr: b = blockIdx&7 (XCD swizzle), 128 queries/block,
// 8 lanes per query. Expanding Chebyshev shells, wave-synchronized R.
// Exactness: after shell R the examined region is the clamped box
// [qc-R, qc+R]; bound = min distance to a NON-clamped face (clamped faces
// unbounded). done when d3 + 1e-3 < bound^2 (margin >> fp rounding in cell
// geometry). R=16 visits every cell => guaranteed exact termination.
// Keys use the R0-proven fmaf expansion => identical ranking; u64
// composite => visit-order independent, exact top_k tie semantics.
__global__ __launch_bounds__(NT, 8) void knn_spatial_kernel(
    const float* __restrict__ xyz1,
    const float4* __restrict__ wpts,
    const unsigned short* __restrict__ wids,
    const unsigned short* __restrict__ wcel,
    const float* __restrict__ points2,
    float* __restrict__ out)
{
    __shared__ float4 s_pts[S_];                 // 32 KB
    __shared__ unsigned short s_ids[S_];         // 4 KB
    __shared__ unsigned short s_cell[CPAD];      // 8.2 KB
    __shared__ float s_w[3][TQ];
    __shared__ int   s_idx[3][TQ];

    const int b  = blockIdx.x & 7;
    const int n0 = (blockIdx.x >> 3) * TQ;
    const int t  = threadIdx.x;
    const int wave = t >> 6, lane = t & 63;
    const int g = t >> 3, sub = t & 7;

    // stage candidate structures (coalesced)
    {
        const float4* src = wpts + (size_t)b * S_;
        for (int i = t; i < S_; i += NT) s_pts[i] = src[i];
        const unsigned int* i32 = (const unsigned int*)(wids + (size_t)b * S_);
        for (int i = t; i < S_/2; i += NT) ((unsigned int*)s_ids)[i] = i32[i];
        const unsigned int* c32 = (const unsigned int*)(wcel + (size_t)b * CPAD);
        for (int i = t; i < NCELL/2; i += NT) ((unsigned int*)s_cell)[i] = c32[i];
        if (t == 0) s_cell[NCELL] = (wcel + (size_t)b * CPAD)[NCELL];
    }
    __syncthreads();

    const int n = n0 + g;
    const float* x1 = xyz1 + (size_t)b * 3 * N_;
    const float ax = x1[n], ay = x1[N_ + n], az = x1[2*N_ + n];
    const float n1a = fmaf(az, az, fmaf(ay, ay, ax * ax));
    const int qcx = min(G_-1, max(0, (int)floorf((ax - XMIN_) * INVW_)));
    const int qcy = min(G_-1, max(0, (int)floorf((ay - XMIN_) * INVW_)));
    const int qcz = min(G_-1, max(0, (int)floorf((az - XMIN_) * INVW_)));

    // PER-LANE accumulators: disjoint candidate sets across the 8 lanes
    // (cell lists partitioned by sub, shells are disjoint cell sets), so
    // no equal composites can ever meet inside one lane's registers.
    unsigned long long m0 = ~0ull, m1 = ~0ull, m2 = ~0ull;
    bool done = false;

    for (int R = 1; R <= G_; ++R) {
        if (__all(done)) break;                      // wave-uniform exit
        for (int dz = -R; dz <= R; ++dz)
        for (int dy = -R; dy <= R; ++dy)
        for (int dx = -R; dx <= R; ++dx) {
            if (R > 1 && abs(dx) < R && abs(dy) < R && abs(dz) < R) continue;
            int cx = qcx + dx, cy = qcy + dy, cz = qcz + dz;
            bool v = !done && (unsigned)cx < G_ && (unsigned)cy < G_
                           && (unsigned)cz < G_;
            int s0 = 0, s1 = 0;
            if (v) {
                int cid = (cz << 8) | (cy << 4) | cx;
                s0 = s_cell[cid]; s1 = s_cell[cid + 1];
            }
            for (int j = s0 + sub; j < s1; j += 8) {
                float4 p = s_pts[j];
                unsigned int id = s_ids[j];
                float key = fmaf(ax, p.x, fmaf(ay, p.y, fmaf(az, p.z, p.w)));
                unsigned int kb = __float_as_uint(key);
                unsigned int sb = kb ^ ((unsigned int)((int)kb >> 31) | 0x80000000u);
                unsigned long long kk = ((unsigned long long)sb << 16) | id;
                ins3u64(kk, m0, m1, m2);
            }
        }
        // NON-DESTRUCTIVE group view for the stop test: butterfly on temp
        // copies (disjoint sources at every step), discarded afterwards.
        unsigned long long r0 = m0, r1 = m1, r2 = m2;
        #pragma unroll
        for (int off = 1; off < 8; off <<= 1) {
            unsigned long long q0 = __shfl_xor(r0, off);
            unsigned long long q1 = __shfl_xor(r1, off);
            unsigned long long q2 = __shfl_xor(r2, off);
            ins3u64(q0, r0, r1, r2);
            ins3u64(q1, r0, r1, r2);
            ins3u64(q2, r0, r1, r2);
        }
        // stopping bound. Sentinel r2 -> NaN d3 -> compare false -> expand.
        unsigned int sb3 = (unsigned int)(r2 >> 16);
        unsigned int kb3 = (sb3 & 0x80000000u) ? (sb3 ^ 0x80000000u) : ~sb3;
        float d3 = __uint_as_float(kb3) + n1a;
        float bnd = 1e30f;
        { int lo = qcx - R, hi = qcx + R;
          if (lo > 0)    bnd = fminf(bnd, ax - (XMIN_ + (float)lo * W_));
          if (hi < G_-1) bnd = fminf(bnd, (XMIN_ + (float)(hi+1) * W_) - ax); }
        { int lo = qcy - R, hi = qcy + R;
          if (lo > 0)    bnd = fminf(bnd, ay - (XMIN_ + (float)lo * W_));
          if (hi < G_-1) bnd = fminf(bnd, (XMIN_ + (float)(hi+1) * W_) - ay); }
        { int lo = qcz - R, hi = qcz + R;
          if (lo > 0)    bnd = fminf(bnd, az - (XMIN_ + (float)lo * W_));
          if (hi < G_-1) bnd = fminf(bnd, (XMIN_ + (float)(hi+1) * W_) - az); }
        done = done || (d3 + 1e-3f < bnd * bnd);
    }

    // FINAL destructive merge: first and only reduce into the real
    // accumulators; per-lane sets are disjoint, butterfly steps combine
    // disjoint unions => no duplicate composites possible.
    #pragma unroll
    for (int off = 1; off < 8; off <<= 1) {
        unsigned long long q0 = __shfl_xor(m0, off);
        unsigned long long q1 = __shfl_xor(m1, off);
        unsigned long long q2 = __shfl_xor(m2, off);
        ins3u64(q0, m0, m1, m2);
        ins3u64(q1, m0, m1, m2);
        ins3u64(q2, m0, m1, m2);
    }

    // epilogue: weights + indices (R2 arithmetic, verbatim)
    if (sub == 0) {
        unsigned int sb0 = (unsigned int)(m0 >> 16);
        unsigned int sb1 = (unsigned int)(m1 >> 16);
        unsigned int sb2 = (unsigned int)(m2 >> 16);
        float e0 = __uint_as_float((sb0 & 0x80000000u) ? (sb0 ^ 0x80000000u) : ~sb0);
        float e1 = __uint_as_float((sb1 & 0x80000000u) ? (sb1 ^ 0x80000000u) : ~sb1);
        float e2 = __uint_as_float((sb2 & 0x80000000u) ? (sb2 ^ 0x80000000u) : ~sb2);
        float r0 = __fdiv_rn(1.0f, __fadd_rn(__fadd_rn(e0, n1a), EPS_));
        float r1 = __fdiv_rn(1.0f, __fadd_rn(__fadd_rn(e1, n1a), EPS_));
        float r2 = __fdiv_rn(1.0f, __fadd_rn(__fadd_rn(e2, n1a), EPS_));
        float rs = __fadd_rn(__fadd_rn(r0, r1), r2);
        s_w[0][g] = __fdiv_rn(r0, rs);
        s_w[1][g] = __fdiv_rn(r1, rs);
        s_w[2][g] = __fdiv_rn(r2, rs);
        s_idx[0][g] = (int)(m0 & 0xFFFFu);
        s_idx[1][g] = (int)(m1 & 0xFFFFu);
        s_idx[2][g] = (int)(m2 & 0xFFFFu);
    }
    __syncthreads();

    // phase C: gather + weighted sum, one wave per query row (16 waves)
    const float* p2 = points2 + (size_t)b * S_ * D_;
    float* op = out + ((size_t)b * N_ + n0) * D_;
    for (int q = wave; q < TQ; q += NT/64) {
        float w0 = s_w[0][q], w1 = s_w[1][q], w2 = s_w[2][q];
        const float4* f0 = (const float4*)(p2 + (size_t)s_idx[0][q] * D_) + lane;
        const float4* f1 = (const float4*)(p2 + (size_t)s_idx[1][q] * D_) + lane;
        const float4* f2 = (const float4*)(p2 + (size_t)s_idx[2][q] * D_) + lane;
        float4 v0 = *f0, v1 = *f1, v2 = *f2;
        float4 r;
        r.x = w0 * v0.x + w1 * v1.x + w2 * v2.x;
        r.y = w0 * v0.y + w1 * v1.y + w2 * v2.y;
        r.z = w0 * v0.z + w1 * v1.z + w2 * v2.z;
        r.w = w0 * v0.w + w1 * v1.w + w2 * v2.w;
        *((float4*)(op + (size_t)q * D_) + lane) = r;
    }
}

/* ---------------- brute-force fallback (proven R2 path) ------------- */
__global__ __launch_bounds__(NTHR, 8) void fp_brute_kernel(
    const float* __restrict__ xyz1,
    const float* __restrict__ xyz2,
    const float* __restrict__ points2,
    float* __restrict__ out)
{
    __shared__ float s_nn[S_] __attribute__((aligned(16)));
    __shared__ float s_pd[NCH][3][TILE_Q];
    __shared__ int   s_pi[NCH][3][TILE_Q];
    __shared__ float s_w[3][TILE_Q];
    __shared__ int   s_idx[3][TILE_Q];

    const int b  = blockIdx.x & 7;
    const int n0 = (blockIdx.x >> 3) * TILE_Q;
    const int t = threadIdx.x;
    const int wave = t >> 6, lane = t & 63;

    const float* x2 = xyz2 + (size_t)b * 3 * S_;
    for (int s = t; s < S_; s += NTHR) {
        float bx = x2[s], by = x2[S_ + s], bz = x2[2 * S_ + s];
        s_nn[s] = fmaf(bz, bz, fmaf(by, by, bx * bx));
    }
    __syncthreads();

    const int n = n0 + lane;
    const float* x1 = xyz1 + (size_t)b * 3 * N_;
    const float ax = x1[n], ay = x1[N_ + n], az = x1[2 * N_ + n];
    const float ax2 = -2.0f * ax, ay2 = -2.0f * ay, az2 = -2.0f * az;

    float a0 = __builtin_inff(), a1 = __builtin_inff(), a2 = __builtin_inff();
    int ja0 = 0, ja1 = 0, ja2 = 0;
    float c0 = __builtin_inff(), c1 = __builtin_inff(), c2 = __builtin_inff();
    int jc0 = 0, jc1 = 0, jc2 = 0;

    const int wu   = __builtin_amdgcn_readfirstlane(wave);
    const int sbeg = wu * CHUNK;
    const float* bxp = x2;
    const float* byp = x2 + S_;
    const float* bzp = x2 + 2 * S_;
    const float4* nn4 = (const float4*)s_nn;
    const int g0 = sbeg >> 2;
    #pragma unroll 2
    for (int g = 0; g < HALF / 4; ++g) {
        float4 nl = nn4[g0 + g];
        float4 nh = nn4[g0 + (HALF >> 2) + g];
        #pragma unroll
        for (int u = 0; u < 4; ++u) {
            const int sl = sbeg + 4 * g + u;
            const int sh = sl + HALF;
            float kl = fmaf(ax2, bxp[sl],
                       fmaf(ay2, byp[sl], fmaf(az2, bzp[sl], (&nl.x)[u])));
            float kh = fmaf(ax2, bxp[sh],
                       fmaf(ay2, byp[sh], fmaf(az2, bzp[sh], (&nh.x)[u])));
            insert3(kl, sl, a0, a1, a2, ja0, ja1, ja2);
            insert3(kh, sh, c0, c1, c2, jc0, jc1, jc2);
        }
    }
    insert3(c0, jc0, a0, a1, a2, ja0, ja1, ja2);
    insert3(c1, jc1, a0, a1, a2, ja0, ja1, ja2);
    insert3(c2, jc2, a0, a1, a2, ja0, ja1, ja2);

    s_pd[wave][0][lane] = a0; s_pd[wave][1][lane] = a1; s_pd[wave][2][lane] = a2;
    s_pi[wave][0][lane] = ja0; s_pi[wave][1][lane] = ja1; s_pi[wave][2][lane] = ja2;
    __syncthreads();

    if (t < TILE_Q) {
        float e0 = __builtin_inff(), e1 = __builtin_inff(), e2 = __builtin_inff();
        int j0 = 0, j1 = 0, j2 = 0;
        #pragma unroll
        for (int c = 0; c < NCH; ++c)
            #pragma unroll
            for (int k = 0; k < 3; ++k)
                insert3(s_pd[c][k][t], s_pi[c][k][t], e0, e1, e2, j0, j1, j2);
        const int nq = n0 + t;
        float qx = x1[nq], qy = x1[N_ + nq], qz = x1[2 * N_ + nq];
        float n1 = fmaf(qz, qz, fmaf(qy, qy, qx * qx));
        float r0 = __fdiv_rn(1.0f, __fadd_rn(__fadd_rn(e0, n1), EPS_));
        float r1 = __fdiv_rn(1.0f, __fadd_rn(__fadd_rn(e1, n1), EPS_));
        float r2 = __fdiv_rn(1.0f, __fadd_rn(__fadd_rn(e2, n1), EPS_));
        float rs = __fadd_rn(__fadd_rn(r0, r1), r2);
        s_w[0][t] = __fdiv_rn(r0, rs);
        s_w[1][t] = __fdiv_rn(r1, rs);
        s_w[2][t] = __fdiv_rn(r2, rs);
        s_idx[0][t] = j0; s_idx[1][t] = j1; s_idx[2][t] = j2;
    }
    __syncthreads();

    const float* p2 = points2 + (size_t)b * S_ * D_;
    float* op = out + ((size_t)b * N_ + n0) * D_;
    for (int q = wave; q < TILE_Q; q += NCH) {
        float w0 = s_w[0][q], w1 = s_w[1][q], w2 = s_w[2][q];
        const float4* f0 = (const float4*)(p2 + (size_t)s_idx[0][q] * D_) + lane;
        const float4* f1 = (const float4*)(p2 + (size_t)s_idx[1][q] * D_) + lane;
        const float4* f2 = (const float4*)(p2 + (size_t)s_idx[2][q] * D_) + lane;
        float4 v0 = *f0, v1 = *f1, v2 = *f2;
        float4 r;
        r.x = w0 * v0.x + w1 * v1.x + w2 * v2.x;
        r.y = w0 * v0.y + w1 * v1.y + w2 * v2.y;
        r.z = w0 * v0.z + w1 * v1.z + w2 * v2.z;
        r.w = w0 * v0.w + w1 * v1.w + w2 * v2.w;
        *((float4*)(op + (size_t)q * D_) + lane) = r;
    }
}

extern "C" void kernel_launch(void* const* d_in, const int* in_sizes, int n_in,
                              void* d_out, int out_size, void* d_ws, size_t ws_size,
                              hipStream_t stream) {
    const float* xyz1    = (const float*)d_in[0];
    const float* xyz2    = (const float*)d_in[1];
    // d_in[2] = points1 is unused by the reference output.
    const float* points2 = (const float*)d_in[3];
    float* out = (float*)d_out;

    if (d_ws && ws_size >= (size_t)WS_NEED) {
        float4*         wpts = (float4*)d_ws;
        unsigned short* wids = (unsigned short*)((char*)d_ws + WS_IDS);
        unsigned short* wcel = (unsigned short*)((char*)d_ws + WS_CEL);
        grid_build_kernel<<<dim3(B_), dim3(256), 0, stream>>>(xyz2, wpts, wids, wcel);
        knn_spatial_kernel<<<dim3(B_ * (N_ / TQ)), dim3(NT), 0, stream>>>(
            xyz1, wpts, wids, wcel, points2, out);
    } else {
        fp_brute_kernel<<<dim3(B_ * (N_ / TILE_Q)), dim3(NTHR), 0, stream>>>(
            xyz1, xyz2, points2, out);
    }
}

// Round 5
// 235.186 us; speedup vs baseline: 2.1523x; 2.1523x over previous
//
#include <hip/hip_runtime.h>

#define B_ 8
#define N_ 8192
#define S_ 2048
#define D_ 256
#define EPS_ 1e-8f

/* ---------------- 1-D x-sort parameters ---------------- */
#define NBX   256
#define XMIN_ (-4.0f)
#define INVW_ 32.0f            /* bin width 1/32 over [-4,4) */
#define CUMP  258              /* cum array padded to even u16 count */

/* workspace layout (bytes) */
#define WS_SID  (B_*S_*16)                 /* wpts: 262144 */
#define WS_CUM  (WS_SID + B_*S_*2)         /* wsid: +32768 = 294912 */
#define WS_QID  (WS_CUM + B_*CUMP*2)       /* wcum: +4128 = 299040 */
#define WS_NEED (WS_QID + B_*N_*2)         /* wqid: +131072 = 430112 */

/* main kernel config: 256 thr = 4 waves; 32 queries x 2 slots per wave */
#define MT 256
#define QB 128                             /* queries per block */

/* ---------------- brute-force fallback params (proven R2 path) ----- */
#define TILE_Q 64
#define NTHR 512
#define NCH 8
#define CHUNK (S_/NCH)
#define HALF (CHUNK/2)

// Branchless stable top-3 insert (float), incumbent wins ties (ascending-
// index visit order only — used by the brute fallback).
__device__ __forceinline__ void insert3(float dd, int s,
                                        float& d0, float& d1, float& d2,
                                        int& i0, int& i1, int& i2) {
    bool ca = dd < d0;
    bool cb = dd < d1;
    bool cc = dd < d2;
    int i2n = cb ? i1 : (cc ? s : i2);
    int i1n = ca ? i0 : (cb ? s : i1);
    int i0n = ca ? s : i0;
    d2 = fminf(d2, fmaxf(d1, dd));
    d1 = __builtin_amdgcn_fmed3f(d0, d1, dd);
    d0 = fminf(d0, dd);
    i0 = i0n; i1 = i1n; i2 = i2n;
}

// Top-3 insert on packed u64 composite (sortable(key)<<16 | idx).
// MERGE DISCIPLINE (R3 lesson): equal composites duplicate; only ever
// combine DISJOINT candidate sets, and never re-reduce an already-merged
// result. Here: each candidate is visited exactly once per query (three
// disjoint ranges x slot parity); slot merge happens once (destructive)
// or into discarded temps (bound probe).
__device__ __forceinline__ void ins3u64(unsigned long long x,
    unsigned long long& d0, unsigned long long& d1, unsigned long long& d2) {
    bool ca = x < d0, cb = x < d1, cc = x < d2;
    d2 = cb ? d1 : (cc ? x : d2);
    d1 = ca ? d0 : (cb ? x : d1);
    d0 = ca ? x : d0;
}

/* ------------- prep: counting-sort candidates by bx, queries by ax ----- */
// blocks 0..7: batch b candidates -> wpts (-2bx,-2by,-2bz,|b|^2) sorted by
//   bx-bin, wsid original idx, wcum[258] bin prefix (u16).
// blocks 8..15: batch b queries -> wqid original idx sorted by ax-bin.
// Order inside a bin is atomic-nondeterministic: harmless (selection is
// visit-order independent; per-query output exact regardless of grouping).
__global__ __launch_bounds__(256) void prep_sort_kernel(
    const float* __restrict__ xyz1, const float* __restrict__ xyz2,
    float4* __restrict__ wpts, unsigned short* __restrict__ wsid,
    unsigned short* __restrict__ wcum, unsigned short* __restrict__ wqid)
{
    __shared__ unsigned int h[NBX];
    __shared__ unsigned int wsum[4];
    __shared__ unsigned char cbin[N_];
    const int blk = blockIdx.x, t = threadIdx.x, lane = t & 63, wv = t >> 6;

    const bool isq = blk >= B_;
    const int b = isq ? blk - B_ : blk;
    const int cnt = isq ? N_ : S_;
    const float* xs = isq ? (xyz1 + (size_t)b*3*N_) : (xyz2 + (size_t)b*3*S_);

    h[t] = 0;
    __syncthreads();
    for (int s = t; s < cnt; s += 256) {
        float x = xs[s];
        int bin = min(NBX-1, max(0, (int)floorf((x - XMIN_) * INVW_)));
        cbin[s] = (unsigned char)bin;
        atomicAdd(&h[bin], 1u);
    }
    __syncthreads();
    // exclusive scan of h[256]: per-wave shfl scan + 4 partials
    unsigned int v = h[t];
    unsigned int incl = v;
    #pragma unroll
    for (int off = 1; off < 64; off <<= 1) {
        unsigned int u = __shfl_up(incl, off);
        if (lane >= off) incl += u;
    }
    if (lane == 63) wsum[wv] = incl;
    __syncthreads();
    unsigned int base = 0;
    for (int w = 0; w < wv; ++w) base += wsum[w];
    unsigned int excl = base + incl - v;
    __syncthreads();
    h[t] = excl;
    if (!isq) {
        unsigned short* cum = wcum + (size_t)b * CUMP;
        cum[t] = (unsigned short)excl;
        if (t == 0) { cum[NBX] = (unsigned short)S_; cum[NBX+1] = (unsigned short)S_; }
    }
    __syncthreads();
    if (!isq) {
        for (int s = t; s < S_; s += 256) {
            unsigned int pos = atomicAdd(&h[cbin[s]], 1u);
            float bx = xs[s], by = xs[S_+s], bz = xs[2*S_+s];
            float nn = fmaf(bz, bz, fmaf(by, by, bx*bx));   // proven fma order
            wpts[(size_t)b*S_ + pos] = make_float4(-2.f*bx, -2.f*by, -2.f*bz, nn);
            wsid[(size_t)b*S_ + pos] = (unsigned short)s;
        }
    } else {
        for (int s = t; s < N_; s += 256) {
            unsigned int pos = atomicAdd(&h[cbin[s]], 1u);
            wqid[(size_t)b*N_ + pos] = (unsigned short)s;
        }
    }
}

/* --------------- slab-pruned exact 3-NN + interpolation ---------------- */
// 512 blocks x 256 thr. Wave = 32 sorted-by-ax queries x 2 slots (slot s
// takes j of parity s). ALL scan ranges are wave-uniform (butterfly union
// + readfirstlane) -> 2-address LDS broadcast reads, zero divergence —
// the R0-proven scan shape, restricted to ~600 instead of 2048 candidates.
// Exactness: pruned candidate has (bx-ax)^2 > d3ub_dist + 1e-3 with d3ub
// the 3rd-smallest key over the >=256-candidate window => its key strictly
// exceeds the final 3rd key (margin >> fma rounding ~3e-5) => cannot enter
// or tie into the top-3. Scanning a SUPERSET of the slab is always exact.
__global__ __launch_bounds__(MT, 2) void knn_slab_kernel(
    const float* __restrict__ xyz1,
    const float4* __restrict__ wpts,
    const unsigned short* __restrict__ wsid,
    const unsigned short* __restrict__ wcum,
    const unsigned short* __restrict__ wqid,
    const float* __restrict__ points2,
    float* __restrict__ out)
{
    __shared__ float4 s_pts[S_];                 // 32 KB, bx-sorted
    __shared__ unsigned short s_ids[S_];         // 4 KB
    __shared__ unsigned short s_cum[CUMP];
    __shared__ unsigned short s_qid[QB];
    __shared__ float s_w[3][QB];
    __shared__ int   s_idx[3][QB];

    const int b    = blockIdx.x & 7;             // batch-per-XCD swizzle
    const int qblk = blockIdx.x >> 3;
    const int t = threadIdx.x;
    const int wave = t >> 6, lane = t & 63;
    const int qi = lane & 31, slot = lane >> 5;

    // stage (coalesced)
    {
        const float4* src = wpts + (size_t)b * S_;
        for (int i = t; i < S_; i += MT) s_pts[i] = src[i];
        const unsigned int* sid32 = (const unsigned int*)(wsid + (size_t)b*S_);
        for (int i = t; i < S_/2; i += MT) ((unsigned int*)s_ids)[i] = sid32[i];
        const unsigned int* cum32 = (const unsigned int*)(wcum + (size_t)b*CUMP);
        if (t < CUMP/2) ((unsigned int*)s_cum)[t] = cum32[t];
        const unsigned int* q32 = (const unsigned int*)(wqid + (size_t)b*N_ + (size_t)qblk*QB);
        if (t < QB/2) ((unsigned int*)s_qid)[t] = q32[t];
    }
    __syncthreads();

    const int q = s_qid[wave*32 + qi];
    const float* x1 = xyz1 + (size_t)b*3*N_;
    const float ax = x1[q], ay = x1[N_+q], az = x1[2*N_+q];
    const float n1a = fmaf(az, az, fmaf(ay, ay, ax*ax));
    const int qbin = min(NBX-1, max(0, (int)floorf((ax - XMIN_)*INVW_)));
    const int cq = s_cum[qbin];

    // wave-uniform window around the queries' rank positions
    int cmin = cq, cmax = cq;
    #pragma unroll
    for (int off = 1; off < 64; off <<= 1) {
        cmin = min(cmin, __shfl_xor(cmin, off));
        cmax = max(cmax, __shfl_xor(cmax, off));
    }
    const int wlo = __builtin_amdgcn_readfirstlane(max(cmin - 128, 0));
    const int whi = __builtin_amdgcn_readfirstlane(min(cmax + 128, S_));

    unsigned long long m0 = ~0ull, m1 = ~0ull, m2 = ~0ull;   // sentinels

    auto scan = [&](int j0, int j1) {
        for (int j = j0 + slot; j < j1; j += 2) {
            float4 p = s_pts[j];
            unsigned int id = s_ids[j];
            float key = fmaf(ax, p.x, fmaf(ay, p.y, fmaf(az, p.z, p.w)));
            unsigned int kb = __float_as_uint(key);
            unsigned int sb = kb ^ ((unsigned int)((int)kb >> 31) | 0x80000000u);
            unsigned long long kk = ((unsigned long long)sb << 16) | id;
            ins3u64(kk, m0, m1, m2);
        }
    };

    // window scan (>=256 candidates; counts toward the final result)
    scan(wlo, whi);

    // per-query d3 upper bound: ONE non-destructive slot merge into temps
    unsigned long long r0 = m0, r1 = m1, r2 = m2;
    {
        unsigned long long t0 = __shfl_xor(r0, 32);
        unsigned long long t1 = __shfl_xor(r1, 32);
        unsigned long long t2 = __shfl_xor(r2, 32);
        ins3u64(t0, r0, r1, r2);
        ins3u64(t1, r0, r1, r2);
        ins3u64(t2, r0, r1, r2);
    }
    unsigned int sb2 = (unsigned int)(r2 >> 16);
    unsigned int kb2 = (sb2 & 0x80000000u) ? (sb2 ^ 0x80000000u) : ~sb2;
    float v2 = __uint_as_float(kb2);                  // 3rd-smallest key (UB)
    float rad = sqrtf(fmaxf(v2 + n1a + 1e-3f, 0.0f)); // slab radius in x
    int lob = min(NBX-1, max(0, (int)floorf((ax - rad - XMIN_)*INVW_)));
    int hib = min(NBX-1, max(0, (int)floorf((ax + rad - XMIN_)*INVW_)));
    int lo = s_cum[lob], hi = s_cum[hib + 1];

    // wave-uniform union of slabs
    int ulo = lo, uhi = hi;
    #pragma unroll
    for (int off = 1; off < 64; off <<= 1) {
        ulo = min(ulo, __shfl_xor(ulo, off));
        uhi = max(uhi, __shfl_xor(uhi, off));
    }
    ulo = __builtin_amdgcn_readfirstlane(ulo);
    uhi = __builtin_amdgcn_readfirstlane(uhi);

    // extensions: disjoint from window, each j visited exactly once
    scan(ulo, wlo);          // empty if ulo >= wlo
    scan(whi, uhi);          // empty if uhi <= whi

    // final destructive slot merge (disjoint parities -> no duplicates)
    {
        unsigned long long t0 = __shfl_xor(m0, 32);
        unsigned long long t1 = __shfl_xor(m1, 32);
        unsigned long long t2 = __shfl_xor(m2, 32);
        ins3u64(t0, m0, m1, m2);
        ins3u64(t1, m0, m1, m2);
        ins3u64(t2, m0, m1, m2);
    }

    // epilogue: weights + indices (proven arithmetic, verbatim)
    if (slot == 0) {
        const int row = wave*32 + qi;
        unsigned int sb0 = (unsigned int)(m0 >> 16);
        unsigned int sb1 = (unsigned int)(m1 >> 16);
        unsigned int sb2b = (unsigned int)(m2 >> 16);
        float e0 = __uint_as_float((sb0 & 0x80000000u) ? (sb0 ^ 0x80000000u) : ~sb0);
        float e1 = __uint_as_float((sb1 & 0x80000000u) ? (sb1 ^ 0x80000000u) : ~sb1);
        float e2 = __uint_as_float((sb2b & 0x80000000u) ? (sb2b ^ 0x80000000u) : ~sb2b);
        float r0f = __fdiv_rn(1.0f, __fadd_rn(__fadd_rn(e0, n1a), EPS_));
        float r1f = __fdiv_rn(1.0f, __fadd_rn(__fadd_rn(e1, n1a), EPS_));
        float r2f = __fdiv_rn(1.0f, __fadd_rn(__fadd_rn(e2, n1a), EPS_));
        float rs = __fadd_rn(__fadd_rn(r0f, r1f), r2f);
        s_w[0][row] = __fdiv_rn(r0f, rs);
        s_w[1][row] = __fdiv_rn(r1f, rs);
        s_w[2][row] = __fdiv_rn(r2f, rs);
        s_idx[0][row] = (int)(m0 & 0xFFFFu);
        s_idx[1][row] = (int)(m1 & 0xFFFFu);
        s_idx[2][row] = (int)(m2 & 0xFFFFu);
    }
    __syncthreads();

    // phase C: gather + weighted sum; one wave per query row (rows scatter
    // to original query ids; each row is a contiguous 1 KB write).
    const float* p2 = points2 + (size_t)b * S_ * D_;
    for (int row = wave; row < QB; row += MT/64) {
        const int oq = s_qid[row];
        float w0 = s_w[0][row], w1 = s_w[1][row], w2 = s_w[2][row];
        float* op = out + ((size_t)b*N_ + oq) * D_;
        const float4* f0 = (const float4*)(p2 + (size_t)s_idx[0][row]*D_) + lane;
        const float4* f1 = (const float4*)(p2 + (size_t)s_idx[1][row]*D_) + lane;
        const float4* f2 = (const float4*)(p2 + (size_t)s_idx[2][row]*D_) + lane;
        float4 v0 = *f0, v1 = *f1, v2v = *f2;
        float4 r;
        r.x = w0*v0.x + w1*v1.x + w2*v2v.x;
        r.y = w0*v0.y + w1*v1.y + w2*v2v.y;
        r.z = w0*v0.z + w1*v1.z + w2*v2v.z;
        r.w = w0*v0.w + w1*v1.w + w2*v2v.w;
        *((float4*)op + lane) = r;
    }
}

/* ---------------- brute-force fallback (proven R2 path) ------------- */
__global__ __launch_bounds__(NTHR, 8) void fp_brute_kernel(
    const float* __restrict__ xyz1,
    const float* __restrict__ xyz2,
    const float* __restrict__ points2,
    float* __restrict__ out)
{
    __shared__ float s_nn[S_] __attribute__((aligned(16)));
    __shared__ float s_pd[NCH][3][TILE_Q];
    __shared__ int   s_pi[NCH][3][TILE_Q];
    __shared__ float s_w[3][TILE_Q];
    __shared__ int   s_idx[3][TILE_Q];

    const int b  = blockIdx.x & 7;
    const int n0 = (blockIdx.x >> 3) * TILE_Q;
    const int t = threadIdx.x;
    const int wave = t >> 6, lane = t & 63;

    const float* x2 = xyz2 + (size_t)b * 3 * S_;
    for (int s = t; s < S_; s += NTHR) {
        float bx = x2[s], by = x2[S_ + s], bz = x2[2 * S_ + s];
        s_nn[s] = fmaf(bz, bz, fmaf(by, by, bx * bx));
    }
    __syncthreads();

    const int n = n0 + lane;
    const float* x1 = xyz1 + (size_t)b * 3 * N_;
    const float ax = x1[n], ay = x1[N_ + n], az = x1[2 * N_ + n];
    const float ax2 = -2.0f * ax, ay2 = -2.0f * ay, az2 = -2.0f * az;

    float a0 = __builtin_inff(), a1 = __builtin_inff(), a2 = __builtin_inff();
    int ja0 = 0, ja1 = 0, ja2 = 0;
    float c0 = __builtin_inff(), c1 = __builtin_inff(), c2 = __builtin_inff();
    int jc0 = 0, jc1 = 0, jc2 = 0;

    const int wu   = __builtin_amdgcn_readfirstlane(wave);
    const int sbeg = wu * CHUNK;
    const float* bxp = x2;
    const float* byp = x2 + S_;
    const float* bzp = x2 + 2 * S_;
    const float4* nn4 = (const float4*)s_nn;
    const int g0 = sbeg >> 2;
    #pragma unroll 2
    for (int g = 0; g < HALF / 4; ++g) {
        float4 nl = nn4[g0 + g];
        float4 nh = nn4[g0 + (HALF >> 2) + g];
        #pragma unroll
        for (int u = 0; u < 4; ++u) {
            const int sl = sbeg + 4 * g + u;
            const int sh = sl + HALF;
            float kl = fmaf(ax2, bxp[sl],
                       fmaf(ay2, byp[sl], fmaf(az2, bzp[sl], (&nl.x)[u])));
            float kh = fmaf(ax2, bxp[sh],
                       fmaf(ay2, byp[sh], fmaf(az2, bzp[sh], (&nh.x)[u])));
            insert3(kl, sl, a0, a1, a2, ja0, ja1, ja2);
            insert3(kh, sh, c0, c1, c2, jc0, jc1, jc2);
        }
    }
    insert3(c0, jc0, a0, a1, a2, ja0, ja1, ja2);
    insert3(c1, jc1, a0, a1, a2, ja0, ja1, ja2);
    insert3(c2, jc2, a0, a1, a2, ja0, ja1, ja2);

    s_pd[wave][0][lane] = a0; s_pd[wave][1][lane] = a1; s_pd[wave][2][lane] = a2;
    s_pi[wave][0][lane] = ja0; s_pi[wave][1][lane] = ja1; s_pi[wave][2][lane] = ja2;
    __syncthreads();

    if (t < TILE_Q) {
        float e0 = __builtin_inff(), e1 = __builtin_inff(), e2 = __builtin_inff();
        int j0 = 0, j1 = 0, j2 = 0;
        #pragma unroll
        for (int c = 0; c < NCH; ++c)
            #pragma unroll
            for (int k = 0; k < 3; ++k)
                insert3(s_pd[c][k][t], s_pi[c][k][t], e0, e1, e2, j0, j1, j2);
        const int nq = n0 + t;
        float qx = x1[nq], qy = x1[N_ + nq], qz = x1[2 * N_ + nq];
        float n1 = fmaf(qz, qz, fmaf(qy, qy, qx * qx));
        float r0 = __fdiv_rn(1.0f, __fadd_rn(__fadd_rn(e0, n1), EPS_));
        float r1 = __fdiv_rn(1.0f, __fadd_rn(__fadd_rn(e1, n1), EPS_));
        float r2 = __fdiv_rn(1.0f, __fadd_rn(__fadd_rn(e2, n1), EPS_));
        float rs = __fadd_rn(__fadd_rn(r0, r1), r2);
        s_w[0][t] = __fdiv_rn(r0, rs);
        s_w[1][t] = __fdiv_rn(r1, rs);
        s_w[2][t] = __fdiv_rn(r2, rs);
        s_idx[0][t] = j0; s_idx[1][t] = j1; s_idx[2][t] = j2;
    }
    __syncthreads();

    const float* p2 = points2 + (size_t)b * S_ * D_;
    float* op = out + ((size_t)b * N_ + n0) * D_;
    for (int qq = wave; qq < TILE_Q; qq += NCH) {
        float w0 = s_w[0][qq], w1 = s_w[1][qq], w2 = s_w[2][qq];
        const float4* f0 = (const float4*)(p2 + (size_t)s_idx[0][qq] * D_) + lane;
        const float4* f1 = (const float4*)(p2 + (size_t)s_idx[1][qq] * D_) + lane;
        const float4* f2 = (const float4*)(p2 + (size_t)s_idx[2][qq] * D_) + lane;
        float4 v0 = *f0, v1 = *f1, v2 = *f2;
        float4 r;
        r.x = w0 * v0.x + w1 * v1.x + w2 * v2.x;
        r.y = w0 * v0.y + w1 * v1.y + w2 * v2.y;
        r.z = w0 * v0.z + w1 * v1.z + w2 * v2.z;
        r.w = w0 * v0.w + w1 * v1.w + w2 * v2.w;
        *((float4*)(op + (size_t)qq * D_) + lane) = r;
    }
}

extern "C" void kernel_launch(void* const* d_in, const int* in_sizes, int n_in,
                              void* d_out, int out_size, void* d_ws, size_t ws_size,
                              hipStream_t stream) {
    const float* xyz1    = (const float*)d_in[0];
    const float* xyz2    = (const float*)d_in[1];
    // d_in[2] = points1 is unused by the reference output.
    const float* points2 = (const float*)d_in[3];
    float* out = (float*)d_out;

    if (d_ws && ws_size >= (size_t)WS_NEED) {
        float4*         wpts = (float4*)d_ws;
        unsigned short* wsid = (unsigned short*)((char*)d_ws + WS_SID);
        unsigned short* wcum = (unsigned short*)((char*)d_ws + WS_CUM);
        unsigned short* wqid = (unsigned short*)((char*)d_ws + WS_QID);
        prep_sort_kernel<<<dim3(2*B_), dim3(256), 0, stream>>>(
            xyz1, xyz2, wpts, wsid, wcum, wqid);
        knn_slab_kernel<<<dim3(B_ * (N_/QB)), dim3(MT), 0, stream>>>(
            xyz1, wpts, wsid, wcum, wqid, points2, out);
    } else {
        fp_brute_kernel<<<dim3(B_ * (N_ / TILE_Q)), dim3(NTHR), 0, stream>>>(
            xyz1, xyz2, points2, out);
    }
}

// Round 6
// 224.977 us; speedup vs baseline: 2.2500x; 1.0454x over previous
//
#include <hip/hip_runtime.h>

#define B_ 8
#define N_ 8192
#define S_ 2048
#define D_ 256
#define EPS_ 1e-8f

/* ---------------- 1-D x-sort parameters ---------------- */
#define NBX   256
#define XMIN_ (-4.0f)
#define INVW_ 32.0f            /* bin width 1/32 over [-4,4) */
#define CUMP  258              /* cum array padded to even u16 count */

/* workspace layout (bytes) */
#define WS_SID  (B_*S_*16)                 /* wpts: 262144 */
#define WS_CUM  (WS_SID + B_*S_*2)         /* wsid: +32768 = 294912 */
#define WS_QID  (WS_CUM + B_*CUMP*2)       /* wcum: +4128 = 299040 */
#define WS_NEED (WS_QID + B_*N_*2)         /* wqid: +131072 = 430112 */

#define QW 32                              /* queries per wave */
#define RING 64                            /* ring growth per side per iter */

/* ---------------- brute-force fallback params (proven R2 path) ----- */
#define TILE_Q 64
#define NTHR 512
#define NCH 8
#define CHUNK (S_/NCH)
#define HALF (CHUNK/2)

// Branchless stable top-3 insert (float), incumbent wins ties (ascending-
// index visit order only — used by the brute fallback).
__device__ __forceinline__ void insert3(float dd, int s,
                                        float& d0, float& d1, float& d2,
                                        int& i0, int& i1, int& i2) {
    bool ca = dd < d0;
    bool cb = dd < d1;
    bool cc = dd < d2;
    int i2n = cb ? i1 : (cc ? s : i2);
    int i1n = ca ? i0 : (cb ? s : i1);
    int i0n = ca ? s : i0;
    d2 = fminf(d2, fmaxf(d1, dd));
    d1 = __builtin_amdgcn_fmed3f(d0, d1, dd);
    d0 = fminf(d0, dd);
    i0 = i0n; i1 = i1n; i2 = i2n;
}

// Top-3 insert on packed u64 composite (sortable(key)<<16 | pos).
// MERGE DISCIPLINE (R3 lesson): equal composites duplicate; only combine
// DISJOINT candidate sets, never re-reduce an already-merged result.
// Here: per-lane accumulators private for the whole search (slot parities
// are disjoint); ring probes merge into DISCARDED temps; exactly one
// destructive slot merge at the end.
__device__ __forceinline__ void ins3u64(unsigned long long x,
    unsigned long long& d0, unsigned long long& d1, unsigned long long& d2) {
    bool ca = x < d0, cb = x < d1, cc = x < d2;
    d2 = cb ? d1 : (cc ? x : d2);
    d1 = ca ? d0 : (cb ? x : d1);
    d0 = ca ? x : d0;
}

/* ------------- prep: counting-sort candidates by bx, queries by ax ----- */
// (R5-proven, verbatim.) blocks 0..7: candidates; 8..15: queries.
__global__ __launch_bounds__(256) void prep_sort_kernel(
    const float* __restrict__ xyz1, const float* __restrict__ xyz2,
    float4* __restrict__ wpts, unsigned short* __restrict__ wsid,
    unsigned short* __restrict__ wcum, unsigned short* __restrict__ wqid)
{
    __shared__ unsigned int h[NBX];
    __shared__ unsigned int wsum[4];
    __shared__ unsigned char cbin[N_];
    const int blk = blockIdx.x, t = threadIdx.x, lane = t & 63, wv = t >> 6;

    const bool isq = blk >= B_;
    const int b = isq ? blk - B_ : blk;
    const int cnt = isq ? N_ : S_;
    const float* xs = isq ? (xyz1 + (size_t)b*3*N_) : (xyz2 + (size_t)b*3*S_);

    h[t] = 0;
    __syncthreads();
    for (int s = t; s < cnt; s += 256) {
        float x = xs[s];
        int bin = min(NBX-1, max(0, (int)floorf((x - XMIN_) * INVW_)));
        cbin[s] = (unsigned char)bin;
        atomicAdd(&h[bin], 1u);
    }
    __syncthreads();
    unsigned int v = h[t];
    unsigned int incl = v;
    #pragma unroll
    for (int off = 1; off < 64; off <<= 1) {
        unsigned int u = __shfl_up(incl, off);
        if (lane >= off) incl += u;
    }
    if (lane == 63) wsum[wv] = incl;
    __syncthreads();
    unsigned int base = 0;
    for (int w = 0; w < wv; ++w) base += wsum[w];
    unsigned int excl = base + incl - v;
    __syncthreads();
    h[t] = excl;
    if (!isq) {
        unsigned short* cum = wcum + (size_t)b * CUMP;
        cum[t] = (unsigned short)excl;
        if (t == 0) { cum[NBX] = (unsigned short)S_; cum[NBX+1] = (unsigned short)S_; }
    }
    __syncthreads();
    if (!isq) {
        for (int s = t; s < S_; s += 256) {
            unsigned int pos = atomicAdd(&h[cbin[s]], 1u);
            float bx = xs[s], by = xs[S_+s], bz = xs[2*S_+s];
            float nn = fmaf(bz, bz, fmaf(by, by, bx*bx));   // proven fma order
            wpts[(size_t)b*S_ + pos] = make_float4(-2.f*bx, -2.f*by, -2.f*bz, nn);
            wsid[(size_t)b*S_ + pos] = (unsigned short)s;
        }
    } else {
        for (int s = t; s < N_; s += 256) {
            unsigned int pos = atomicAdd(&h[cbin[s]], 1u);
            wqid[(size_t)b*N_ + pos] = (unsigned short)s;
        }
    }
}

/* --------- expanding-ring exact 3-NN + interpolation (1 wave/block) ----- */
// 2048 blocks x 64 thr (8 waves/CU). Wave = 32 sorted-by-ax queries x 2
// slots (parity split). NO LDS staging, NO barriers in the search: the
// bx-sorted candidate stream is read directly from global (L1/L2-resident;
// per wave-iter the 2 slots touch 32 CONTIGUOUS bytes -> one broadcast).
// Expanding rank-ring: start with the +-64 rank window, then grow 64/side
// while any query's provable slab [cum[bin(ax-rad)], cum[bin(ax+rad)+1])
// exceeds the scanned range; rad = sqrt(d3ub+1e-3) from the current merged
// top-3 (non-destructive probe). Exactness: unscanned candidate => outside
// every bin of the slab => |bx-ax| > rad => key > d3ub >= final d3 (margin
// 1e-3 >> fma rounding ~1e-5) => cannot enter or tie into the top-3.
// Composite idx = sorted position (ties broken by position, not original
// id: distinct on continuous random data); remapped via wsid at the end.
__global__ __launch_bounds__(64, 4) void knn_ring_kernel(
    const float* __restrict__ xyz1,
    const float4* __restrict__ wpts,
    const unsigned short* __restrict__ wsid,
    const unsigned short* __restrict__ wcum,
    const unsigned short* __restrict__ wqid,
    const float* __restrict__ points2,
    float* __restrict__ out)
{
    __shared__ float s_w[3][QW];
    __shared__ int   s_idx[3][QW];
    __shared__ int   s_oq[QW];

    const int b    = blockIdx.x & 7;             // batch-per-XCD swizzle
    const int qblk = blockIdx.x >> 3;
    const int lane = threadIdx.x;
    const int qi = lane & 31, slot = lane >> 5;

    const unsigned short* cum = wcum + (size_t)b * CUMP;
    const int q = wqid[(size_t)b * N_ + qblk * QW + qi];
    const float* x1 = xyz1 + (size_t)b*3*N_;
    const float ax = x1[q], ay = x1[N_+q], az = x1[2*N_+q];
    const float n1a = fmaf(az, az, fmaf(ay, ay, ax*ax));
    const int qbin = min(NBX-1, max(0, (int)floorf((ax - XMIN_)*INVW_)));
    const int cq = cum[qbin];

    // wave-uniform initial window around the 32 queries' rank positions
    int cmin = cq, cmax = cq;
    #pragma unroll
    for (int off = 1; off < 64; off <<= 1) {
        cmin = min(cmin, __shfl_xor(cmin, off));
        cmax = max(cmax, __shfl_xor(cmax, off));
    }
    int wlo = __builtin_amdgcn_readfirstlane(max(cmin - 64, 0));
    int whi = __builtin_amdgcn_readfirstlane(min(cmax + 64, S_));

    const float4* pts4 = wpts + (size_t)b * S_;
    unsigned long long m0 = ~0ull, m1 = ~0ull, m2 = ~0ull;   // sentinels

    auto scan = [&](int j0, int j1) {
        #pragma unroll 4
        for (int j = j0 + slot; j < j1; j += 2) {
            float4 p = pts4[j];
            float key = fmaf(ax, p.x, fmaf(ay, p.y, fmaf(az, p.z, p.w)));
            unsigned int kb = __float_as_uint(key);
            unsigned int sb = kb ^ ((unsigned int)((int)kb >> 31) | 0x80000000u);
            unsigned long long kk = ((unsigned long long)sb << 16) | (unsigned)j;
            ins3u64(kk, m0, m1, m2);
        }
    };

    scan(wlo, whi);                               // >=128 cands per query

    for (int it = 0; it < 32; ++it) {
        // non-destructive probe: merged d3 upper bound (temps discarded)
        unsigned long long r0 = m0, r1 = m1, r2 = m2;
        {
            unsigned long long t0 = __shfl_xor(r0, 32);
            unsigned long long t1 = __shfl_xor(r1, 32);
            unsigned long long t2 = __shfl_xor(r2, 32);
            ins3u64(t0, r0, r1, r2);
            ins3u64(t1, r0, r1, r2);
            ins3u64(t2, r0, r1, r2);
        }
        unsigned int sb2 = (unsigned int)(r2 >> 16);
        unsigned int kb2 = (sb2 & 0x80000000u) ? (sb2 ^ 0x80000000u) : ~sb2;
        float rad = sqrtf(fmaxf(__uint_as_float(kb2) + n1a + 1e-3f, 0.0f));
        int lob = min(NBX-1, max(0, (int)floorf((ax - rad - XMIN_)*INVW_)));
        int hib = min(NBX-1, max(0, (int)floorf((ax + rad - XMIN_)*INVW_)));
        int lo = cum[lob], hi = cum[hib + 1];
        bool needL = lo < wlo, needR = hi > whi;   // auto-false at hard edges
        if (!__any(needL || needR)) break;
        int nlo = __any(needL) ? max(wlo - RING, 0) : wlo;
        int nhi = __any(needR) ? min(whi + RING, S_) : whi;
        scan(nlo, wlo);                            // disjoint extensions
        scan(whi, nhi);
        wlo = nlo; whi = nhi;
    }

    // single destructive slot merge (disjoint parities -> no duplicates)
    {
        unsigned long long t0 = __shfl_xor(m0, 32);
        unsigned long long t1 = __shfl_xor(m1, 32);
        unsigned long long t2 = __shfl_xor(m2, 32);
        ins3u64(t0, m0, m1, m2);
        ins3u64(t1, m0, m1, m2);
        ins3u64(t2, m0, m1, m2);
    }

    // epilogue: weights (proven arithmetic) + sorted-pos -> original id
    if (slot == 0) {
        const unsigned short* sid = wsid + (size_t)b * S_;
        unsigned int sb0 = (unsigned int)(m0 >> 16);
        unsigned int sb1 = (unsigned int)(m1 >> 16);
        unsigned int sb2b = (unsigned int)(m2 >> 16);
        float e0 = __uint_as_float((sb0 & 0x80000000u) ? (sb0 ^ 0x80000000u) : ~sb0);
        float e1 = __uint_as_float((sb1 & 0x80000000u) ? (sb1 ^ 0x80000000u) : ~sb1);
        float e2 = __uint_as_float((sb2b & 0x80000000u) ? (sb2b ^ 0x80000000u) : ~sb2b);
        float r0f = __fdiv_rn(1.0f, __fadd_rn(__fadd_rn(e0, n1a), EPS_));
        float r1f = __fdiv_rn(1.0f, __fadd_rn(__fadd_rn(e1, n1a), EPS_));
        float r2f = __fdiv_rn(1.0f, __fadd_rn(__fadd_rn(e2, n1a), EPS_));
        float rs = __fadd_rn(__fadd_rn(r0f, r1f), r2f);
        s_w[0][qi] = __fdiv_rn(r0f, rs);
        s_w[1][qi] = __fdiv_rn(r1f, rs);
        s_w[2][qi] = __fdiv_rn(r2f, rs);
        s_idx[0][qi] = sid[(int)(m0 & 0xFFFFu)];
        s_idx[1][qi] = sid[(int)(m1 & 0xFFFFu)];
        s_idx[2][qi] = sid[(int)(m2 & 0xFFFFu)];
        s_oq[qi] = q;
    }
    __syncthreads();   // single wave: near-free; orders LDS for phase C

    // phase C: gather + weighted sum; 32 rows x 64 lanes x float4 (D=256)
    const float* p2 = points2 + (size_t)b * S_ * D_;
    #pragma unroll 2
    for (int row = 0; row < QW; ++row) {
        float w0 = s_w[0][row], w1 = s_w[1][row], w2 = s_w[2][row];
        float* op = out + ((size_t)b*N_ + s_oq[row]) * D_;
        const float4* f0 = (const float4*)(p2 + (size_t)s_idx[0][row]*D_) + lane;
        const float4* f1 = (const float4*)(p2 + (size_t)s_idx[1][row]*D_) + lane;
        const float4* f2 = (const float4*)(p2 + (size_t)s_idx[2][row]*D_) + lane;
        float4 v0 = *f0, v1 = *f1, v2v = *f2;
        float4 r;
        r.x = w0*v0.x + w1*v1.x + w2*v2v.x;
        r.y = w0*v0.y + w1*v1.y + w2*v2v.y;
        r.z = w0*v0.z + w1*v1.z + w2*v2v.z;
        r.w = w0*v0.w + w1*v1.w + w2*v2v.w;
        *((float4*)op + lane) = r;
    }
}

/* ---------------- brute-force fallback (proven R2 path) ------------- */
__global__ __launch_bounds__(NTHR, 8) void fp_brute_kernel(
    const float* __restrict__ xyz1,
    const float* __restrict__ xyz2,
    const float* __restrict__ points2,
    float* __restrict__ out)
{
    __shared__ float s_nn[S_] __attribute__((aligned(16)));
    __shared__ float s_pd[NCH][3][TILE_Q];
    __shared__ int   s_pi[NCH][3][TILE_Q];
    __shared__ float s_w[3][TILE_Q];
    __shared__ int   s_idx[3][TILE_Q];

    const int b  = blockIdx.x & 7;
    const int n0 = (blockIdx.x >> 3) * TILE_Q;
    const int t = threadIdx.x;
    const int wave = t >> 6, lane = t & 63;

    const float* x2 = xyz2 + (size_t)b * 3 * S_;
    for (int s = t; s < S_; s += NTHR) {
        float bx = x2[s], by = x2[S_ + s], bz = x2[2 * S_ + s];
        s_nn[s] = fmaf(bz, bz, fmaf(by, by, bx * bx));
    }
    __syncthreads();

    const int n = n0 + lane;
    const float* x1 = xyz1 + (size_t)b * 3 * N_;
    const float ax = x1[n], ay = x1[N_ + n], az = x1[2 * N_ + n];
    const float ax2 = -2.0f * ax, ay2 = -2.0f * ay, az2 = -2.0f * az;

    float a0 = __builtin_inff(), a1 = __builtin_inff(), a2 = __builtin_inff();
    int ja0 = 0, ja1 = 0, ja2 = 0;
    float c0 = __builtin_inff(), c1 = __builtin_inff(), c2 = __builtin_inff();
    int jc0 = 0, jc1 = 0, jc2 = 0;

    const int wu   = __builtin_amdgcn_readfirstlane(wave);
    const int sbeg = wu * CHUNK;
    const float* bxp = x2;
    const float* byp = x2 + S_;
    const float* bzp = x2 + 2 * S_;
    const float4* nn4 = (const float4*)s_nn;
    const int g0 = sbeg >> 2;
    #pragma unroll 2
    for (int g = 0; g < HALF / 4; ++g) {
        float4 nl = nn4[g0 + g];
        float4 nh = nn4[g0 + (HALF >> 2) + g];
        #pragma unroll
        for (int u = 0; u < 4; ++u) {
            const int sl = sbeg + 4 * g + u;
            const int sh = sl + HALF;
            float kl = fmaf(ax2, bxp[sl],
                       fmaf(ay2, byp[sl], fmaf(az2, bzp[sl], (&nl.x)[u])));
            float kh = fmaf(ax2, bxp[sh],
                       fmaf(ay2, byp[sh], fmaf(az2, bzp[sh], (&nh.x)[u])));
            insert3(kl, sl, a0, a1, a2, ja0, ja1, ja2);
            insert3(kh, sh, c0, c1, c2, jc0, jc1, jc2);
        }
    }
    insert3(c0, jc0, a0, a1, a2, ja0, ja1, ja2);
    insert3(c1, jc1, a0, a1, a2, ja0, ja1, ja2);
    insert3(c2, jc2, a0, a1, a2, ja0, ja1, ja2);

    s_pd[wave][0][lane] = a0; s_pd[wave][1][lane] = a1; s_pd[wave][2][lane] = a2;
    s_pi[wave][0][lane] = ja0; s_pi[wave][1][lane] = ja1; s_pi[wave][2][lane] = ja2;
    __syncthreads();

    if (t < TILE_Q) {
        float e0 = __builtin_inff(), e1 = __builtin_inff(), e2 = __builtin_inff();
        int j0 = 0, j1 = 0, j2 = 0;
        #pragma unroll
        for (int c = 0; c < NCH; ++c)
            #pragma unroll
            for (int k = 0; k < 3; ++k)
                insert3(s_pd[c][k][t], s_pi[c][k][t], e0, e1, e2, j0, j1, j2);
        const int nq = n0 + t;
        float qx = x1[nq], qy = x1[N_ + nq], qz = x1[2 * N_ + nq];
        float n1 = fmaf(qz, qz, fmaf(qy, qy, qx * qx));
        float r0 = __fdiv_rn(1.0f, __fadd_rn(__fadd_rn(e0, n1), EPS_));
        float r1 = __fdiv_rn(1.0f, __fadd_rn(__fadd_rn(e1, n1), EPS_));
        float r2 = __fdiv_rn(1.0f, __fadd_rn(__fadd_rn(e2, n1), EPS_));
        float rs = __fadd_rn(__fadd_rn(r0, r1), r2);
        s_w[0][t] = __fdiv_rn(r0, rs);
        s_w[1][t] = __fdiv_rn(r1, rs);
        s_w[2][t] = __fdiv_rn(r2, rs);
        s_idx[0][t] = j0; s_idx[1][t] = j1; s_idx[2][t] = j2;
    }
    __syncthreads();

    const float* p2 = points2 + (size_t)b * S_ * D_;
    float* op = out + ((size_t)b * N_ + n0) * D_;
    for (int qq = wave; qq < TILE_Q; qq += NCH) {
        float w0 = s_w[0][qq], w1 = s_w[1][qq], w2 = s_w[2][qq];
        const float4* f0 = (const float4*)(p2 + (size_t)s_idx[0][qq] * D_) + lane;
        const float4* f1 = (const float4*)(p2 + (size_t)s_idx[1][qq] * D_) + lane;
        const float4* f2 = (const float4*)(p2 + (size_t)s_idx[2][qq] * D_) + lane;
        float4 v0 = *f0, v1 = *f1, v2 = *f2;
        float4 r;
        r.x = w0 * v0.x + w1 * v1.x + w2 * v2.x;
        r.y = w0 * v0.y + w1 * v1.y + w2 * v2.y;
        r.z = w0 * v0.z + w1 * v1.z + w2 * v2.z;
        r.w = w0 * v0.w + w1 * v1.w + w2 * v2.w;
        *((float4*)(op + (size_t)qq * D_) + lane) = r;
    }
}

extern "C" void kernel_launch(void* const* d_in, const int* in_sizes, int n_in,
                              void* d_out, int out_size, void* d_ws, size_t ws_size,
                              hipStream_t stream) {
    const float* xyz1    = (const float*)d_in[0];
    const float* xyz2    = (const float*)d_in[1];
    // d_in[2] = points1 is unused by the reference output.
    const float* points2 = (const float*)d_in[3];
    float* out = (float*)d_out;

    if (d_ws && ws_size >= (size_t)WS_NEED) {
        float4*         wpts = (float4*)d_ws;
        unsigned short* wsid = (unsigned short*)((char*)d_ws + WS_SID);
        unsigned short* wcum = (unsigned short*)((char*)d_ws + WS_CUM);
        unsigned short* wqid = (unsigned short*)((char*)d_ws + WS_QID);
        prep_sort_kernel<<<dim3(2*B_), dim3(256), 0, stream>>>(
            xyz1, xyz2, wpts, wsid, wcum, wqid);
        knn_ring_kernel<<<dim3(B_ * (N_/QW)), dim3(64), 0, stream>>>(
            xyz1, wpts, wsid, wcum, wqid, points2, out);
    } else {
        fp_brute_kernel<<<dim3(B_ * (N_ / TILE_Q)), dim3(NTHR), 0, stream>>>(
            xyz1, xyz2, points2, out);
    }
}

// Round 7
// 177.724 us; speedup vs baseline: 2.8482x; 1.2659x over previous
//
#include <hip/hip_runtime.h>

#define B_ 8
#define N_ 8192
#define S_ 2048
#define D_ 256
#define EPS_ 1e-8f

/* ---------------- 1-D x-sort parameters ---------------- */
#define NBX   256
#define XMIN_ (-4.0f)
#define INVW_ 32.0f            /* bin width 1/32 over [-4,4) */
#define CUMP  258              /* cum array padded to even u16 count */

/* workspace layout (bytes) */
#define WS_SID  (B_*S_*16)                 /* wpts: 262144 */
#define WS_CUM  (WS_SID + B_*S_*2)         /* wsid: +32768 = 294912 */
#define WS_QID  (WS_CUM + B_*CUMP*2)       /* wcum: +4128 = 299040 */
#define WS_NEED (WS_QID + B_*N_*2)         /* wqid: +131072 = 430112 */

#define QW 8                               /* queries per wave (8 slots each) */
#define QBLK 32                            /* queries per 256-thr block */

/* ---------------- brute-force fallback params (proven R2 path) ----- */
#define TILE_Q 64
#define NTHR 512
#define NCH 8
#define CHUNK (S_/NCH)
#define HALF (CHUNK/2)

// Branchless stable top-3 insert (float), incumbent wins ties (ascending-
// index visit order only — used by the brute fallback).
__device__ __forceinline__ void insert3(float dd, int s,
                                        float& d0, float& d1, float& d2,
                                        int& i0, int& i1, int& i2) {
    bool ca = dd < d0;
    bool cb = dd < d1;
    bool cc = dd < d2;
    int i2n = cb ? i1 : (cc ? s : i2);
    int i1n = ca ? i0 : (cb ? s : i1);
    int i0n = ca ? s : i0;
    d2 = fminf(d2, fmaxf(d1, dd));
    d1 = __builtin_amdgcn_fmed3f(d0, d1, dd);
    d0 = fminf(d0, dd);
    i0 = i0n; i1 = i1n; i2 = i2n;
}

// Top-3 insert on packed u64 composite (sortable(key)<<16 | pos).
// MERGE DISCIPLINE (R3 lesson): equal composites duplicate; only combine
// DISJOINT candidate sets, never re-reduce an already-merged result.
// Here: per-lane accumulators private for the whole search (slot classes
// are disjoint); the d3ub probe merges into DISCARDED temps; exactly one
// destructive slot merge at the end.
__device__ __forceinline__ void ins3u64(unsigned long long x,
    unsigned long long& d0, unsigned long long& d1, unsigned long long& d2) {
    bool ca = x < d0, cb = x < d1, cc = x < d2;
    d2 = cb ? d1 : (cc ? x : d2);
    d1 = ca ? d0 : (cb ? x : d1);
    d0 = ca ? x : d0;
}

/* ------------- prep: counting-sort candidates by bx, queries by ax ----- */
// (R5/R6-proven, verbatim.) blocks 0..7: candidates; 8..15: queries.
__global__ __launch_bounds__(256) void prep_sort_kernel(
    const float* __restrict__ xyz1, const float* __restrict__ xyz2,
    float4* __restrict__ wpts, unsigned short* __restrict__ wsid,
    unsigned short* __restrict__ wcum, unsigned short* __restrict__ wqid)
{
    __shared__ unsigned int h[NBX];
    __shared__ unsigned int wsum[4];
    __shared__ unsigned char cbin[N_];
    const int blk = blockIdx.x, t = threadIdx.x, lane = t & 63, wv = t >> 6;

    const bool isq = blk >= B_;
    const int b = isq ? blk - B_ : blk;
    const int cnt = isq ? N_ : S_;
    const float* xs = isq ? (xyz1 + (size_t)b*3*N_) : (xyz2 + (size_t)b*3*S_);

    h[t] = 0;
    __syncthreads();
    for (int s = t; s < cnt; s += 256) {
        float x = xs[s];
        int bin = min(NBX-1, max(0, (int)floorf((x - XMIN_) * INVW_)));
        cbin[s] = (unsigned char)bin;
        atomicAdd(&h[bin], 1u);
    }
    __syncthreads();
    unsigned int v = h[t];
    unsigned int incl = v;
    #pragma unroll
    for (int off = 1; off < 64; off <<= 1) {
        unsigned int u = __shfl_up(incl, off);
        if (lane >= off) incl += u;
    }
    if (lane == 63) wsum[wv] = incl;
    __syncthreads();
    unsigned int base = 0;
    for (int w = 0; w < wv; ++w) base += wsum[w];
    unsigned int excl = base + incl - v;
    __syncthreads();
    h[t] = excl;
    if (!isq) {
        unsigned short* cum = wcum + (size_t)b * CUMP;
        cum[t] = (unsigned short)excl;
        if (t == 0) { cum[NBX] = (unsigned short)S_; cum[NBX+1] = (unsigned short)S_; }
    }
    __syncthreads();
    if (!isq) {
        for (int s = t; s < S_; s += 256) {
            unsigned int pos = atomicAdd(&h[cbin[s]], 1u);
            float bx = xs[s], by = xs[S_+s], bz = xs[2*S_+s];
            float nn = fmaf(bz, bz, fmaf(by, by, bx*bx));   // proven fma order
            wpts[(size_t)b*S_ + pos] = make_float4(-2.f*bx, -2.f*by, -2.f*bz, nn);
            wsid[(size_t)b*S_ + pos] = (unsigned short)s;
        }
    } else {
        for (int s = t; s < N_; s += 256) {
            unsigned int pos = atomicAdd(&h[cbin[s]], 1u);
            wqid[(size_t)b*N_ + pos] = (unsigned short)s;
        }
    }
}

/* ------ one-shot slab exact 3-NN + interpolation (8 slots/query) ------- */
// 2048 blocks x 256 thr = 8192 waves (8/SIMD target). Wave = 8 sorted
// queries x 8 slots; lane = qi*8 + slot. Per scan iteration the 8 slots
// read 8 CONSECUTIVE float4s (128 contiguous bytes -> one fetch,
// broadcast to the 8 qi-groups). ONE-SHOT schedule (R5-proven exactness):
//   scan(window +-128 rank) -> probe d3ub (temps, discarded) ->
//   slab = [cum[bin(ax-rad)], cum[bin(ax+rad)+1]) union over wave ->
//   scan(slab \ window) -> single destructive slot merge.
// Unscanned candidate => bin outside slab => |bx-ax| > rad =>
// dist^2 > d3ub + 1e-3 (margin >> fma rounding) => cannot enter/tie top-3.
// Composite idx = sorted position (distinct keys on continuous data);
// remapped via wsid at the end.
__global__ __launch_bounds__(256, 8) void knn8_kernel(
    const float* __restrict__ xyz1,
    const float4* __restrict__ wpts,
    const unsigned short* __restrict__ wsid,
    const unsigned short* __restrict__ wcum,
    const unsigned short* __restrict__ wqid,
    const float* __restrict__ points2,
    float* __restrict__ out)
{
    __shared__ float s_w[3][QBLK];
    __shared__ int   s_idx[3][QBLK];
    __shared__ int   s_oq[QBLK];

    const int b    = blockIdx.x & 7;             // batch-per-XCD swizzle
    const int qblk = blockIdx.x >> 3;
    const int t = threadIdx.x;
    const int wave = t >> 6, wl = t & 63;
    const int qi = wl >> 3, slot = wl & 7;
    const int row = wave * QW + qi;              // 0..31 within block

    const unsigned short* cum = wcum + (size_t)b * CUMP;
    const int q = wqid[(size_t)b * N_ + qblk * QBLK + row];
    const float* x1 = xyz1 + (size_t)b*3*N_;
    const float ax = x1[q], ay = x1[N_+q], az = x1[2*N_+q];
    const float n1a = fmaf(az, az, fmaf(ay, ay, ax*ax));
    const int qbin = min(NBX-1, max(0, (int)floorf((ax - XMIN_)*INVW_)));
    const int cq = cum[qbin];

    // wave-uniform window around this wave's 8 queries (xor 8/16/32 spans qi)
    int cmin = cq, cmax = cq;
    #pragma unroll
    for (int off = 8; off < 64; off <<= 1) {
        cmin = min(cmin, __shfl_xor(cmin, off));
        cmax = max(cmax, __shfl_xor(cmax, off));
    }
    // full-wave broadcast of the extremes (also covers slot dimension)
    #pragma unroll
    for (int off = 1; off < 8; off <<= 1) {
        cmin = min(cmin, __shfl_xor(cmin, off));
        cmax = max(cmax, __shfl_xor(cmax, off));
    }
    const int wlo = __builtin_amdgcn_readfirstlane(max(cmin - 128, 0));
    const int whi = __builtin_amdgcn_readfirstlane(min(cmax + 128, S_));

    const float4* pts4 = wpts + (size_t)b * S_;
    unsigned long long m0 = ~0ull, m1 = ~0ull, m2 = ~0ull;   // sentinels

    auto scan = [&](int j0, int j1) {
        #pragma unroll 4
        for (int j = j0 + slot; j < j1; j += 8) {
            float4 p = pts4[j];
            float key = fmaf(ax, p.x, fmaf(ay, p.y, fmaf(az, p.z, p.w)));
            unsigned int kb = __float_as_uint(key);
            unsigned int sb = kb ^ ((unsigned int)((int)kb >> 31) | 0x80000000u);
            unsigned long long kk = ((unsigned long long)sb << 16) | (unsigned)j;
            ins3u64(kk, m0, m1, m2);
        }
    };

    scan(wlo, whi);          // >=128 candidates seen by every query

    // ONE non-destructive probe: per-query d3 upper bound (xor 1/2/4 = slots)
    unsigned long long r0 = m0, r1 = m1, r2 = m2;
    #pragma unroll
    for (int off = 1; off < 8; off <<= 1) {
        unsigned long long t0 = __shfl_xor(r0, off);
        unsigned long long t1 = __shfl_xor(r1, off);
        unsigned long long t2 = __shfl_xor(r2, off);
        ins3u64(t0, r0, r1, r2);
        ins3u64(t1, r0, r1, r2);
        ins3u64(t2, r0, r1, r2);
    }
    unsigned int sb2 = (unsigned int)(r2 >> 16);
    unsigned int kb2 = (sb2 & 0x80000000u) ? (sb2 ^ 0x80000000u) : ~sb2;
    float rad = sqrtf(fmaxf(__uint_as_float(kb2) + n1a + 1e-3f, 0.0f));
    int lob = min(NBX-1, max(0, (int)floorf((ax - rad - XMIN_)*INVW_)));
    int hib = min(NBX-1, max(0, (int)floorf((ax + rad - XMIN_)*INVW_)));
    int lo = cum[lob], hi = cum[hib + 1];

    // wave-uniform slab union
    int ulo = lo, uhi = hi;
    #pragma unroll
    for (int off = 1; off < 64; off <<= 1) {
        ulo = min(ulo, __shfl_xor(ulo, off));
        uhi = max(uhi, __shfl_xor(uhi, off));
    }
    ulo = __builtin_amdgcn_readfirstlane(ulo);
    uhi = __builtin_amdgcn_readfirstlane(uhi);

    // disjoint extensions (each j visited exactly once per query)
    scan(ulo, wlo);
    scan(whi, uhi);

    // single destructive slot merge (disjoint slot classes -> no dups)
    #pragma unroll
    for (int off = 1; off < 8; off <<= 1) {
        unsigned long long t0 = __shfl_xor(m0, off);
        unsigned long long t1 = __shfl_xor(m1, off);
        unsigned long long t2 = __shfl_xor(m2, off);
        ins3u64(t0, m0, m1, m2);
        ins3u64(t1, m0, m1, m2);
        ins3u64(t2, m0, m1, m2);
    }

    // epilogue: weights (proven arithmetic) + sorted-pos -> original id
    if (slot == 0) {
        const unsigned short* sid = wsid + (size_t)b * S_;
        unsigned int sb0 = (unsigned int)(m0 >> 16);
        unsigned int sb1 = (unsigned int)(m1 >> 16);
        unsigned int sb2b = (unsigned int)(m2 >> 16);
        float e0 = __uint_as_float((sb0 & 0x80000000u) ? (sb0 ^ 0x80000000u) : ~sb0);
        float e1 = __uint_as_float((sb1 & 0x80000000u) ? (sb1 ^ 0x80000000u) : ~sb1);
        float e2 = __uint_as_float((sb2b & 0x80000000u) ? (sb2b ^ 0x80000000u) : ~sb2b);
        float r0f = __fdiv_rn(1.0f, __fadd_rn(__fadd_rn(e0, n1a), EPS_));
        float r1f = __fdiv_rn(1.0f, __fadd_rn(__fadd_rn(e1, n1a), EPS_));
        float r2f = __fdiv_rn(1.0f, __fadd_rn(__fadd_rn(e2, n1a), EPS_));
        float rs = __fadd_rn(__fadd_rn(r0f, r1f), r2f);
        s_w[0][row] = __fdiv_rn(r0f, rs);
        s_w[1][row] = __fdiv_rn(r1f, rs);
        s_w[2][row] = __fdiv_rn(r2f, rs);
        s_idx[0][row] = sid[(int)(m0 & 0xFFFFu)];
        s_idx[1][row] = sid[(int)(m1 & 0xFFFFu)];
        s_idx[2][row] = sid[(int)(m2 & 0xFFFFu)];
        s_oq[row] = q;
    }
    __syncthreads();

    // phase C: gather + weighted sum; 32 rows, 4 waves, 64 lanes x float4
    const float* p2 = points2 + (size_t)b * S_ * D_;
    for (int r = wave; r < QBLK; r += 4) {
        float w0 = s_w[0][r], w1 = s_w[1][r], w2 = s_w[2][r];
        float* op = out + ((size_t)b*N_ + s_oq[r]) * D_;
        const float4* f0 = (const float4*)(p2 + (size_t)s_idx[0][r]*D_) + wl;
        const float4* f1 = (const float4*)(p2 + (size_t)s_idx[1][r]*D_) + wl;
        const float4* f2 = (const float4*)(p2 + (size_t)s_idx[2][r]*D_) + wl;
        float4 v0 = *f0, v1 = *f1, v2v = *f2;
        float4 r4;
        r4.x = w0*v0.x + w1*v1.x + w2*v2v.x;
        r4.y = w0*v0.y + w1*v1.y + w2*v2v.y;
        r4.z = w0*v0.z + w1*v1.z + w2*v2v.z;
        r4.w = w0*v0.w + w1*v1.w + w2*v2v.w;
        *((float4*)op + wl) = r4;
    }
}

/* ---------------- brute-force fallback (proven R2 path) ------------- */
__global__ __launch_bounds__(NTHR, 8) void fp_brute_kernel(
    const float* __restrict__ xyz1,
    const float* __restrict__ xyz2,
    const float* __restrict__ points2,
    float* __restrict__ out)
{
    __shared__ float s_nn[S_] __attribute__((aligned(16)));
    __shared__ float s_pd[NCH][3][TILE_Q];
    __shared__ int   s_pi[NCH][3][TILE_Q];
    __shared__ float s_w[3][TILE_Q];
    __shared__ int   s_idx[3][TILE_Q];

    const int b  = blockIdx.x & 7;
    const int n0 = (blockIdx.x >> 3) * TILE_Q;
    const int t = threadIdx.x;
    const int wave = t >> 6, lane = t & 63;

    const float* x2 = xyz2 + (size_t)b * 3 * S_;
    for (int s = t; s < S_; s += NTHR) {
        float bx = x2[s], by = x2[S_ + s], bz = x2[2 * S_ + s];
        s_nn[s] = fmaf(bz, bz, fmaf(by, by, bx * bx));
    }
    __syncthreads();

    const int n = n0 + lane;
    const float* x1 = xyz1 + (size_t)b * 3 * N_;
    const float ax = x1[n], ay = x1[N_ + n], az = x1[2 * N_ + n];
    const float ax2 = -2.0f * ax, ay2 = -2.0f * ay, az2 = -2.0f * az;

    float a0 = __builtin_inff(), a1 = __builtin_inff(), a2 = __builtin_inff();
    int ja0 = 0, ja1 = 0, ja2 = 0;
    float c0 = __builtin_inff(), c1 = __builtin_inff(), c2 = __builtin_inff();
    int jc0 = 0, jc1 = 0, jc2 = 0;

    const int wu   = __builtin_amdgcn_readfirstlane(wave);
    const int sbeg = wu * CHUNK;
    const float* bxp = x2;
    const float* byp = x2 + S_;
    const float* bzp = x2 + 2 * S_;
    const float4* nn4 = (const float4*)s_nn;
    const int g0 = sbeg >> 2;
    #pragma unroll 2
    for (int g = 0; g < HALF / 4; ++g) {
        float4 nl = nn4[g0 + g];
        float4 nh = nn4[g0 + (HALF >> 2) + g];
        #pragma unroll
        for (int u = 0; u < 4; ++u) {
            const int sl = sbeg + 4 * g + u;
            const int sh = sl + HALF;
            float kl = fmaf(ax2, bxp[sl],
                       fmaf(ay2, byp[sl], fmaf(az2, bzp[sl], (&nl.x)[u])));
            float kh = fmaf(ax2, bxp[sh],
                       fmaf(ay2, byp[sh], fmaf(az2, bzp[sh], (&nh.x)[u])));
            insert3(kl, sl, a0, a1, a2, ja0, ja1, ja2);
            insert3(kh, sh, c0, c1, c2, jc0, jc1, jc2);
        }
    }
    insert3(c0, jc0, a0, a1, a2, ja0, ja1, ja2);
    insert3(c1, jc1, a0, a1, a2, ja0, ja1, ja2);
    insert3(c2, jc2, a0, a1, a2, ja0, ja1, ja2);

    s_pd[wave][0][lane] = a0; s_pd[wave][1][lane] = a1; s_pd[wave][2][lane] = a2;
    s_pi[wave][0][lane] = ja0; s_pi[wave][1][lane] = ja1; s_pi[wave][2][lane] = ja2;
    __syncthreads();

    if (t < TILE_Q) {
        float e0 = __builtin_inff(), e1 = __builtin_inff(), e2 = __builtin_inff();
        int j0 = 0, j1 = 0, j2 = 0;
        #pragma unroll
        for (int c = 0; c < NCH; ++c)
            #pragma unroll
            for (int k = 0; k < 3; ++k)
                insert3(s_pd[c][k][t], s_pi[c][k][t], e0, e1, e2, j0, j1, j2);
        const int nq = n0 + t;
        float qx = x1[nq], qy = x1[N_ + nq], qz = x1[2 * N_ + nq];
        float n1 = fmaf(qz, qz, fmaf(qy, qy, qx * qx));
        float r0 = __fdiv_rn(1.0f, __fadd_rn(__fadd_rn(e0, n1), EPS_));
        float r1 = __fdiv_rn(1.0f, __fadd_rn(__fadd_rn(e1, n1), EPS_));
        float r2 = __fdiv_rn(1.0f, __fadd_rn(__fadd_rn(e2, n1), EPS_));
        float rs = __fadd_rn(__fadd_rn(r0, r1), r2);
        s_w[0][t] = __fdiv_rn(r0, rs);
        s_w[1][t] = __fdiv_rn(r1, rs);
        s_w[2][t] = __fdiv_rn(r2, rs);
        s_idx[0][t] = j0; s_idx[1][t] = j1; s_idx[2][t] = j2;
    }
    __syncthreads();

    const float* p2 = points2 + (size_t)b * S_ * D_;
    float* op = out + ((size_t)b * N_ + n0) * D_;
    for (int qq = wave; qq < TILE_Q; qq += NCH) {
        float w0 = s_w[0][qq], w1 = s_w[1][qq], w2 = s_w[2][qq];
        const float4* f0 = (const float4*)(p2 + (size_t)s_idx[0][qq] * D_) + lane;
        const float4* f1 = (const float4*)(p2 + (size_t)s_idx[1][qq] * D_) + lane;
        const float4* f2 = (const float4*)(p2 + (size_t)s_idx[2][qq] * D_) + lane;
        float4 v0 = *f0, v1 = *f1, v2 = *f2;
        float4 r;
        r.x = w0 * v0.x + w1 * v1.x + w2 * v2.x;
        r.y = w0 * v0.y + w1 * v1.y + w2 * v2.y;
        r.z = w0 * v0.z + w1 * v1.z + w2 * v2.z;
        r.w = w0 * v0.w + w1 * v1.w + w2 * v2.w;
        *((float4*)(op + (size_t)qq * D_) + lane) = r;
    }
}

extern "C" void kernel_launch(void* const* d_in, const int* in_sizes, int n_in,
                              void* d_out, int out_size, void* d_ws, size_t ws_size,
                              hipStream_t stream) {
    const float* xyz1    = (const float*)d_in[0];
    const float* xyz2    = (const float*)d_in[1];
    // d_in[2] = points1 is unused by the reference output.
    const float* points2 = (const float*)d_in[3];
    float* out = (float*)d_out;

    if (d_ws && ws_size >= (size_t)WS_NEED) {
        float4*         wpts = (float4*)d_ws;
        unsigned short* wsid = (unsigned short*)((char*)d_ws + WS_SID);
        unsigned short* wcum = (unsigned short*)((char*)d_ws + WS_CUM);
        unsigned short* wqid = (unsigned short*)((char*)d_ws + WS_QID);
        prep_sort_kernel<<<dim3(2*B_), dim3(256), 0, stream>>>(
            xyz1, xyz2, wpts, wsid, wcum, wqid);
        knn8_kernel<<<dim3(B_ * (N_/QBLK)), dim3(256), 0, stream>>>(
            xyz1, wpts, wsid, wcum, wqid, points2, out);
    } else {
        fp_brute_kernel<<<dim3(B_ * (N_ / TILE_Q)), dim3(NTHR), 0, stream>>>(
            xyz1, xyz2, points2, out);
    }
}